// Round 3
// baseline (211.169 us; speedup 1.0000x reference)
//
#include <hip/hip_runtime.h>
#include <hip/hip_bf16.h>
#include <stdint.h>

#define S_LEN 1024
#define HDIM  1024
#define NHEADS 16
#define HEAD_D 64
#define KSEL  512
#define BATCH 8

typedef unsigned short ushort_t;
typedef __attribute__((ext_vector_type(8))) __bf16 bf16x8;
typedef __attribute__((ext_vector_type(4))) float  f32x4;

typedef const __attribute__((address_space(1))) void cg_void;
typedef __attribute__((address_space(3))) void lds_void;

__device__ __forceinline__ void gl_lds16(const void* g, void* l) {
    __builtin_amdgcn_global_load_lds((cg_void*)g, (lds_void*)l, 16, 0, 0);
}

// round-to-nearest-even f32 -> bf16 (finite inputs only)
__device__ __forceinline__ ushort_t f2bf(float f) {
    union { float f; unsigned int i; } x; x.f = f;
    unsigned int r = (x.i + 0x7fffu + ((x.i >> 16) & 1u)) >> 16;
    return (ushort_t)r;
}

// ---------------- kernel 0: prep = cvt(hidden,Wq,Wk,Wv) + compact -----------
// pos[b][s] = slot (<512) or -1 : inverse permutation for gemm's Q scatter.
__global__ __launch_bounds__(1024) void prep_kernel(
    const float* __restrict__ hidden, const float* __restrict__ wq,
    const float* __restrict__ wk, const float* __restrict__ wv,
    const int* __restrict__ remain,
    ushort_t* __restrict__ hbf, ushort_t* __restrict__ wqb,
    ushort_t* __restrict__ wkb, ushort_t* __restrict__ wvb,
    short* __restrict__ pos, int* __restrict__ valid) {
    __shared__ int wsum[16];
    __shared__ int woff[17];
    int blk = blockIdx.x;
    if (blk < 2816) {
        const float* s; ushort_t* d; int base;
        if (blk < 2048)      { s = hidden; d = hbf; base = blk; }
        else if (blk < 2304) { s = wq; d = wqb; base = blk - 2048; }
        else if (blk < 2560) { s = wk; d = wkb; base = blk - 2304; }
        else                 { s = wv; d = wvb; base = blk - 2560; }
        int i = base * 1024 + threadIdx.x;
        float4 v = ((const float4*)s)[i];
        ushort4 o;
        o.x = f2bf(v.x); o.y = f2bf(v.y); o.z = f2bf(v.z); o.w = f2bf(v.w);
        ((ushort4*)d)[i] = o;
    } else {
        int b = blk - 2816, t = threadIdx.x;
        int r = remain[b * S_LEN + t];
        unsigned long long m = __ballot(r != 0);
        int lane = t & 63, w = t >> 6;
        int pre = __popcll(m & ((1ull << lane) - 1ull));
        if (lane == 0) wsum[w] = __popcll(m);
        __syncthreads();
        if (t == 0) { int a = 0; for (int i = 0; i < 16; i++) { woff[i] = a; a += wsum[i]; } woff[16] = a; }
        __syncthreads();
        int tot = woff[16];
        int onesBefore = woff[w] + pre;
        int slot = r ? onesBefore : (tot + (t - onesBefore));
        pos[b * S_LEN + t] = (short)((slot < KSEL) ? slot : -1);
        if (slot < KSEL) valid[b * KSEL + slot] = r;
    }
}

// ---------------- kernel 1: unified projection GEMM, 256^2, deep-ring -------
// C[8192][3072] = hbf @ [Wk;Wv;Wq]^T.  384 blocks x 512 thr (8 waves 2Mx4N),
// per-wave 128x64, acc[8][4].  BK=32, 4-slot LDS ring per operand
// (4 x 16KB A + 4 x 16KB B = 128 KiB), staged 3 K-tiles AHEAD.
// R2 post-mortem: barrier-locked 8-phase at 1 block/CU capped in-flight DMA
// at ~64KB/CU -> 8 B/cyc/CU staging (vs 15.5 at R1's 4 blocks/CU).  This
// version keeps ~96KB/CU in flight continuously: ONE barrier + ONE counted
// vmcnt(8) per u-iter, no phase micro-barriers; compiler schedules
// ds_read/MFMA freely (it does this well, m97).
// Ring hazard proof: stage(u+3) writes slot (u+3)&3 == (u-1)&3; the barrier
// at top of u guarantees all waves finished reading slot (u-1) (reads happen
// before their vmcnt+BAR).  Read of slot u needs stage(u) complete: end of
// u-1 waits vmcnt(8) -> oldest 4 issues (= stage(u)) drained.  Tail: u=29
// vmcnt(4), u=30 vmcnt(0).
// LDS swizzle both-sides (rule #21): 16B chunk ^= (row&3) on the pre-swizzled
// GLOBAL source and on the ds_read address (gl_lds writes linearly).
#define QSCALE 0.1803368801111244f
#define LT_PITCH 264
#define BAR() __asm__ volatile("s_barrier" ::: "memory")
#define VMCNT(n) __asm__ volatile("s_waitcnt vmcnt(" #n ")" ::: "memory")

__global__ __launch_bounds__(512, 2) void gemm8(
    const ushort_t* __restrict__ hbf, const ushort_t* __restrict__ wkvq,
    const float* __restrict__ bk, const float* __restrict__ bv,
    const float* __restrict__ bq,
    const short* __restrict__ pos, const int* __restrict__ valid,
    ushort_t* __restrict__ kp, ushort_t* __restrict__ vt, ushort_t* __restrict__ qp) {
    __shared__ __align__(16) ushort_t pool[65536];   // 128 KiB: A ring | B ring
    const int i = blockIdx.x;
    const int swz = (i & 7) * 48 + (i >> 3);         // 384 = 8*48, bijective
    const int bmI = swz / 12, bnI = swz % 12;
    const int bm = bmI * 256;
    const int bn = bnI * 256;

    const int tid = threadIdx.x;
    const int lane = tid & 63;
    const int w = tid >> 6;
    const int quad = lane >> 4;
    const int cl = lane & 15;
    const int wr = w >> 2;                 // 0..1: row half (128 rows)
    const int wc = w & 3;                  // 0..3: col quarter (64 cols)

    // staging: issue i covers chunk c = i*512+tid of a 256x32 tile (2048 16B
    // chunks); row = c>>2, col16 = c&3, source col16 ^= row&3.
    const int sr = tid >> 2;                                  // row within half
    const int scol = ((tid & 3) ^ (sr & 3)) * 8;              // elems
    const ushort_t* aSrc = hbf  + (bm + sr) * 1024 + scol;
    const ushort_t* bSrc = wkvq + (bn + sr) * 1024 + scol;
    const int dOff = tid * 8;                                 // elems

    // fragment reads: row r -> elem r*32 + ((quad ^ (r&3))*8); r&3 == cl&3
    const int ksw = (quad ^ (cl & 3)) * 8;
    const int aR0 = wr * 128;
    const int bR0 = wc * 64;

    auto stage = [&](int kt) {
        const int sl = (kt & 3) * 8192;
        const ushort_t* sa = aSrc + kt * 32;
        const ushort_t* sb = bSrc + kt * 32;
        gl_lds16(sa,                &pool[sl + dOff]);
        gl_lds16(sa + 131072,       &pool[sl + 4096 + dOff]);        // +128 rows
        gl_lds16(sb,                &pool[32768 + sl + dOff]);
        gl_lds16(sb + 131072,       &pool[32768 + sl + 4096 + dOff]);
    };

    f32x4 acc[8][4] = {};

    stage(0); stage(1); stage(2);
    VMCNT(8);                               // slot 0 ready

    for (int u = 0; u < 32; ++u) {
        BAR();
        if (u < 29) stage(u + 3);
        const int sl = (u & 3) * 8192;
        bf16x8 bf[4];
#pragma unroll
        for (int nt = 0; nt < 4; nt++)
            bf[nt] = *(const bf16x8*)&pool[32768 + sl + (bR0 + nt * 16 + cl) * 32 + ksw];
#pragma unroll
        for (int mt = 0; mt < 8; mt++) {
            bf16x8 af = *(const bf16x8*)&pool[sl + (aR0 + mt * 16 + cl) * 32 + ksw];
#pragma unroll
            for (int nt = 0; nt < 4; nt++)
                acc[mt][nt] = __builtin_amdgcn_mfma_f32_16x16x32_bf16(af, bf[nt], acc[mt][nt], 0, 0, 0);
        }
        if (u < 29)      VMCNT(8);          // drain stage(u+1); keep 8 in flight
        else if (u == 29) VMCNT(4);
        else if (u == 30) VMCNT(0);
    }

    // ---------------- epilogues (verbatim from R2, verified) ----------------
    const int row0 = bm + wr * 128;
    const int colW = wc * 64;
    if (bnI < 4) {
        const int cb = bn + colW;
#pragma unroll
        for (int nt = 0; nt < 4; nt++) {
            int col = cb + nt * 16 + cl;
            float bb = bk[col];
#pragma unroll
            for (int mt = 0; mt < 8; mt++) {
                int rw = row0 + mt * 16 + quad * 4;
#pragma unroll
                for (int r = 0; r < 4; r++)
                    kp[(rw + r) * 1024 + col] = f2bf(acc[mt][nt][r] + bb);
            }
        }
    } else if (bnI < 8) {
        const int vcb = bn - 1024;
        const int b_ = bm >> 10;
        const int s0 = bm & 1023;
#pragma unroll
        for (int p2 = 0; p2 < 2; p2++) {
            if ((wc >> 1) == p2) {
#pragma unroll
                for (int nt = 0; nt < 4; nt++) {
                    int cloc = (wc & 1) * 64 + nt * 16 + cl;   // 0..127
                    float bb = bv[vcb + p2 * 128 + cloc];
#pragma unroll
                    for (int mt = 0; mt < 8; mt++) {
                        int rr = wr * 128 + mt * 16 + quad * 4;
#pragma unroll
                        for (int r = 0; r < 4; r++)
                            pool[cloc * LT_PITCH + rr + r] = f2bf(acc[mt][nt][r] + bb);
                    }
                }
            }
            __syncthreads();
            {
                int col = tid >> 2;            // 0..127
                int sq = tid & 3;
                int gb = ((b_ << 10) + vcb + p2 * 128 + col) * 1024 + s0;
                const ushort_t* src = &pool[col * LT_PITCH];
#pragma unroll
                for (int j = 0; j < 8; j++) {
                    int ch = (sq + 4 * j) * 8;
                    *(bf16x8*)(vt + gb + ch) = *(const bf16x8*)(src + ch);
                }
            }
            __syncthreads();
        }
    } else {
        const int qcb = bn - 2048 + colW;
        float bqv[4];
#pragma unroll
        for (int nt = 0; nt < 4; nt++) bqv[nt] = bq[qcb + nt * 16 + cl];
#pragma unroll
        for (int mt = 0; mt < 8; mt++) {
#pragma unroll
            for (int r = 0; r < 4; r++) {
                int row = row0 + mt * 16 + quad * 4 + r;
                int p = pos[row];
                if (p >= 0) {
                    float vm = (float)valid[((row >> 10) << 9) + p];
                    int ob = ((row >> 10) * 512 + p) * 1024 + qcb;
#pragma unroll
                    for (int nt = 0; nt < 4; nt++)
                        qp[ob + nt * 16 + cl] = f2bf((acc[mt][nt][r] * vm + bqv[nt]) * QSCALE);
                }
            }
        }
    }
}

// ---------------- kernel 2: flash attention, 32 q-rows per wave -------------
// R1 attn + mask hoisted to LDS once per block (premultiplied by log2e):
// removes 4 scalar global loads (~200cy L2 latency) from the per-iter
// QK->exp2 critical path.
#define P_PITCH 72
__global__ __launch_bounds__(256, 2) void attn_kernel(
    const ushort_t* __restrict__ qp, const ushort_t* __restrict__ kp,
    const ushort_t* __restrict__ vt, const float* __restrict__ mask,
    float* __restrict__ out) {
    __shared__ __align__(16) ushort_t ks[2][4096];
    __shared__ __align__(16) ushort_t vs[2][4096];
    __shared__ __align__(16) ushort_t ps[4][32 * P_PITCH];
    __shared__ float mlds[1024];
    const int tid = threadIdx.x;
    const int lane = tid & 63;
    const int w = tid >> 6;
    const int quad = lane >> 4;
    const int cl = lane & 15;
    const int qt = blockIdx.x, h = blockIdx.y, b = blockIdx.z;

    const int srow = tid >> 2;
    const int fsa = ((tid >> 2) & 3) ^ ((tid >> 4) & 3);
    const int sc8 = ((tid & 3) ^ fsa) * 8;
    const int lds_off = tid * 8;
    const int fr = (cl & 3) ^ ((cl >> 2) & 3);
    const int qo = (quad ^ fr) * 8;

    const long kbase = (long)b * S_LEN;
    const long vbase = (long)b * 1024 + h * HEAD_D;

    // mask -> LDS (premultiplied by log2e)
    {
        float4 mv4 = *(const float4*)(mask + b * S_LEN + tid * 4);
        mlds[tid * 4 + 0] = mv4.x * 1.44269504f;
        mlds[tid * 4 + 1] = mv4.y * 1.44269504f;
        mlds[tid * 4 + 2] = mv4.z * 1.44269504f;
        mlds[tid * 4 + 3] = mv4.w * 1.44269504f;
    }

    const long qrow0 = (long)b * KSEL + qt * 128 + w * 32;
    bf16x8 aq[2][2];
#pragma unroll
    for (int mt = 0; mt < 2; mt++)
#pragma unroll
        for (int kk = 0; kk < 2; kk++)
            aq[mt][kk] = *(const bf16x8*)(qp + (qrow0 + mt * 16 + cl) * HDIM + h * HEAD_D + kk * 32 + quad * 8);

    f32x4 O[2][4] = {};
    float l_r[2][4] = {};

#pragma unroll
    for (int j = 0; j < 2; j++) {
        gl_lds16(kp + (kbase + srow) * (long)HDIM + h * HEAD_D + j * 32 + sc8, &ks[0][j * 2048 + lds_off]);
        gl_lds16(vt + (vbase + srow) * (long)S_LEN + j * 32 + sc8, &vs[0][j * 2048 + lds_off]);
    }

    for (int c = 0; c < S_LEN / 64; c++) {
        __asm__ volatile("s_waitcnt vmcnt(0)" ::: "memory");
        __syncthreads();
        if (c + 1 < S_LEN / 64) {
            int nb = (c + 1) & 1;
#pragma unroll
            for (int j = 0; j < 2; j++) {
                gl_lds16(kp + (kbase + (c + 1) * 64 + srow) * (long)HDIM + h * HEAD_D + j * 32 + sc8,
                         &ks[nb][j * 2048 + lds_off]);
                gl_lds16(vt + (vbase + srow) * (long)S_LEN + (c + 1) * 64 + j * 32 + sc8,
                         &vs[nb][j * 2048 + lds_off]);
            }
        }
        const ushort_t* kbuf = ks[c & 1];
        const ushort_t* vbuf = vs[c & 1];

        f32x4 sc[2][4] = {};
#pragma unroll
        for (int kk = 0; kk < 2; kk++)
#pragma unroll
            for (int nt = 0; nt < 4; nt++) {
                bf16x8 bk8 = *(const bf16x8*)&kbuf[kk * 2048 + (nt * 16 + cl) * 32 + qo];
#pragma unroll
                for (int mt = 0; mt < 2; mt++)
                    sc[mt][nt] = __builtin_amdgcn_mfma_f32_16x16x32_bf16(aq[mt][kk], bk8, sc[mt][nt], 0, 0, 0);
            }

#pragma unroll
        for (int nt = 0; nt < 4; nt++) {
            float mv = mlds[c * 64 + nt * 16 + cl];
#pragma unroll
            for (int mt = 0; mt < 2; mt++)
#pragma unroll
                for (int r = 0; r < 4; r++) {
                    float p_ = __builtin_amdgcn_exp2f(sc[mt][nt][r] + mv);
                    sc[mt][nt][r] = p_;
                    l_r[mt][r] += p_;
                }
        }

#pragma unroll
        for (int mt = 0; mt < 2; mt++)
#pragma unroll
            for (int nt = 0; nt < 4; nt++)
#pragma unroll
                for (int r = 0; r < 4; r++)
                    ps[w][(mt * 16 + quad * 4 + r) * P_PITCH + nt * 16 + cl] = f2bf(sc[mt][nt][r]);

        __asm__ volatile("s_waitcnt lgkmcnt(0)" ::: "memory");

#pragma unroll
        for (int kk = 0; kk < 2; kk++) {
            bf16x8 ap[2];
#pragma unroll
            for (int mt = 0; mt < 2; mt++)
                ap[mt] = *(const bf16x8*)&ps[w][(mt * 16 + cl) * P_PITCH + kk * 32 + quad * 8];
#pragma unroll
            for (int dt = 0; dt < 4; dt++) {
                bf16x8 bv8 = *(const bf16x8*)&vbuf[kk * 2048 + (dt * 16 + cl) * 32 + qo];
#pragma unroll
                for (int mt = 0; mt < 2; mt++)
                    O[mt][dt] = __builtin_amdgcn_mfma_f32_16x16x32_bf16(ap[mt], bv8, O[mt][dt], 0, 0, 0);
            }
        }
    }

#pragma unroll
    for (int mt = 0; mt < 2; mt++)
#pragma unroll
        for (int r = 0; r < 4; r++) {
            float s0 = l_r[mt][r];
#pragma unroll
            for (int d = 1; d < 16; d <<= 1) s0 += __shfl_xor(s0, d, 64);
            l_r[mt][r] = s0;
        }

#pragma unroll
    for (int mt = 0; mt < 2; mt++) {
        const long orow0 = qrow0 + mt * 16 + quad * 4;
#pragma unroll
        for (int dt = 0; dt < 4; dt++) {
            int col = h * HEAD_D + dt * 16 + cl;
#pragma unroll
            for (int r = 0; r < 4; r++)
                out[(orow0 + r) * HDIM + col] = O[mt][dt][r] / l_r[mt][r];
        }
    }
}

// ---------------- launch ----------------------------------------------------
extern "C" void kernel_launch(void* const* d_in, const int* in_sizes, int n_in,
                              void* d_out, int out_size, void* d_ws, size_t ws_size,
                              hipStream_t stream) {
    const float* hidden = (const float*)d_in[0];
    const float* mask   = (const float*)d_in[1];
    const int*   remain = (const int*)d_in[2];
    const float* Wq = (const float*)d_in[3];
    const float* bq = (const float*)d_in[4];
    const float* Wk = (const float*)d_in[5];
    const float* bk = (const float*)d_in[6];
    const float* Wv = (const float*)d_in[7];
    const float* bv = (const float*)d_in[8];
    float* out = (float*)d_out;

    char* ws = (char*)d_ws;
    size_t off = 0;
    short* pos   = (short*)(ws + off); off += 16384;
    int* valid = (int*)(ws + off); off += 16384;
    ushort_t* hbf  = (ushort_t*)(ws + off); off += (size_t)BATCH * S_LEN * HDIM * 2;
    ushort_t* wkvq = (ushort_t*)(ws + off); off += (size_t)3 * HDIM * HDIM * 2;
    ushort_t* qp  = (ushort_t*)(ws + off); off += (size_t)BATCH * KSEL * HDIM * 2;
    ushort_t* kp  = (ushort_t*)(ws + off); off += (size_t)BATCH * S_LEN * HDIM * 2;
    ushort_t* vt  = (ushort_t*)(ws + off); off += (size_t)BATCH * S_LEN * HDIM * 2;

    prep_kernel<<<2824, 1024, 0, stream>>>(hidden, Wq, Wk, Wv, remain,
                                           hbf, wkvq + 2 * 1048576, wkvq,
                                           wkvq + 1048576, pos, valid);
    gemm8<<<384, 512, 0, stream>>>(hbf, wkvq, bk, bv, bq, pos, valid, kp, vt, qp);
    attn_kernel<<<dim3(4, NHEADS, BATCH), 256, 0, stream>>>(qp, kp, vt, mask, out);
}

// Round 5
// 190.396 us; speedup vs baseline: 1.1091x; 1.1091x over previous
//
#include <hip/hip_runtime.h>
#include <hip/hip_bf16.h>
#include <stdint.h>

#define S_LEN 1024
#define HDIM  1024
#define NHEADS 16
#define HEAD_D 64
#define KSEL  512
#define BATCH 8

typedef unsigned short ushort_t;
typedef __attribute__((ext_vector_type(8))) __bf16 bf16x8;
typedef __attribute__((ext_vector_type(4))) float  f32x4;
typedef __attribute__((ext_vector_type(16))) float f32x16;

typedef const __attribute__((address_space(1))) void cg_void;
typedef __attribute__((address_space(3))) void lds_void;

__device__ __forceinline__ void gl_lds16(const void* g, void* l) {
    __builtin_amdgcn_global_load_lds((cg_void*)g, (lds_void*)l, 16, 0, 0);
}

// round-to-nearest-even f32 -> bf16 (finite inputs only)
__device__ __forceinline__ ushort_t f2bf(float f) {
    union { float f; unsigned int i; } x; x.f = f;
    unsigned int r = (x.i + 0x7fffu + ((x.i >> 16) & 1u)) >> 16;
    return (ushort_t)r;
}

// ---------------- kernel 0: prep = cvt(hidden,Wq,Wk,Wv) + compact -----------
__global__ __launch_bounds__(1024) void prep_kernel(
    const float* __restrict__ hidden, const float* __restrict__ wq,
    const float* __restrict__ wk, const float* __restrict__ wv,
    const int* __restrict__ remain,
    ushort_t* __restrict__ hbf, ushort_t* __restrict__ wqb,
    ushort_t* __restrict__ wkb, ushort_t* __restrict__ wvb,
    int* __restrict__ idx, int* __restrict__ valid) {
    __shared__ int wsum[16];
    __shared__ int woff[17];
    int blk = blockIdx.x;
    if (blk < 2816) {
        const float* s; ushort_t* d; int base;
        if (blk < 2048)      { s = hidden; d = hbf; base = blk; }
        else if (blk < 2304) { s = wq; d = wqb; base = blk - 2048; }
        else if (blk < 2560) { s = wk; d = wkb; base = blk - 2304; }
        else                 { s = wv; d = wvb; base = blk - 2560; }
        int i = base * 1024 + threadIdx.x;
        float4 v = ((const float4*)s)[i];
        ushort4 o;
        o.x = f2bf(v.x); o.y = f2bf(v.y); o.z = f2bf(v.z); o.w = f2bf(v.w);
        ((ushort4*)d)[i] = o;
    } else {
        int b = blk - 2816, t = threadIdx.x;
        int r = remain[b * S_LEN + t];
        unsigned long long m = __ballot(r != 0);
        int lane = t & 63, w = t >> 6;
        int pre = __popcll(m & ((1ull << lane) - 1ull));
        if (lane == 0) wsum[w] = __popcll(m);
        __syncthreads();
        if (t == 0) { int a = 0; for (int i = 0; i < 16; i++) { woff[i] = a; a += wsum[i]; } woff[16] = a; }
        __syncthreads();
        int tot = woff[16];
        int onesBefore = woff[w] + pre;
        int slot = r ? onesBefore : (tot + (t - onesBefore));
        if (slot < KSEL) { idx[b * KSEL + slot] = t; valid[b * KSEL + slot] = r; }
    }
}

// ---------------- kernel 1: fused K/V/Q projection GEMM (R1, verified) ------
// 128^2 tiles, BK=64, 4 blocks/CU: measured 63.4-64.0 us.  R2/R3 established
// that 256^2 single-block-per-CU schedules LOSE here (staging-concurrency-
// bound, ~8 B/cyc/CU vs 15.5 at 4 blocks/CU).  Do not revisit without a
// lever that raises per-CU DMA concurrency.
#define QSCALE 0.1803368801111244f
#define LT_PITCH 136
__global__ __launch_bounds__(256, 4) void gemm_fused(
    const ushort_t* __restrict__ hbf, const ushort_t* __restrict__ wkv,
    const ushort_t* __restrict__ wq,
    const float* __restrict__ bk, const float* __restrict__ bv,
    const float* __restrict__ bq,
    const int* __restrict__ idx, const int* __restrict__ valid,
    ushort_t* __restrict__ kp, ushort_t* __restrict__ vt, ushort_t* __restrict__ qp) {
    __shared__ __align__(16) ushort_t pool[16384];   // 32 KB: As 8192 | Bs 8192
    ushort_t* As = pool;
    ushort_t* Bs = pool + 8192;
    const int i = blockIdx.x;
    int z, bmI, bnI;
    if (i < 256) { z = 1; bmI = i >> 3; bnI = i & 7; }
    else         { z = 0; int ii = i - 256; int x = ii & 7, j = ii >> 3;
                   bmI = x * 8 + (j >> 4); bnI = j & 15; }
    const long bm = (long)bmI * 128;
    const int bn = bnI * 128;

    const int tid = threadIdx.x;
    const int lane = tid & 63;
    const int w = tid >> 6;
    const int quad = lane >> 4;
    const int cl = lane & 15;
    const int srow = w * 16 + (lane >> 2);
    const int fs = ((lane >> 2) & 3) ^ ((lane >> 4) & 3);
    const int scol = ((lane & 3) ^ fs) * 8;
    const int lds_off = w * 512 + lane * 8;
    const int wr = (w >> 1) * 64, wc = (w & 1) * 64;
    const int fr = (cl & 3) ^ ((cl >> 2) & 3);
    const int qo = (quad ^ fr) * 8;

    const ushort_t* W = z ? wq : wkv;

    long ab[2];
#pragma unroll
    for (int p = 0; p < 2; p++) {
        long gr = bm + p * 64 + srow;
        if (z == 0) ab[p] = gr * HDIM;
        else {
            int b_ = (int)(gr >> 9);
            int src = idx[(b_ << 9) + ((int)gr & 511)];
            ab[p] = ((long)(b_ << 10) + src) * HDIM;
        }
    }

    f32x4 acc[4][4] = {};

    for (int k0 = 0; k0 < HDIM; k0 += 64) {
#pragma unroll
        for (int p = 0; p < 2; p++)
#pragma unroll
            for (int hh = 0; hh < 2; hh++) {
                gl_lds16(hbf + ab[p] + k0 + hh * 32 + scol, &As[hh * 4096 + p * 2048 + lds_off]);
                gl_lds16(W + ((long)(bn + p * 64 + srow)) * HDIM + k0 + hh * 32 + scol,
                         &Bs[hh * 4096 + p * 2048 + lds_off]);
            }
        __syncthreads();
#pragma unroll
        for (int hh = 0; hh < 2; hh++) {
            bf16x8 af[4], bfr[4];
#pragma unroll
            for (int mt = 0; mt < 4; mt++)
                af[mt] = *(const bf16x8*)&As[hh * 4096 + (wr + mt * 16 + cl) * 32 + qo];
#pragma unroll
            for (int nt = 0; nt < 4; nt++)
                bfr[nt] = *(const bf16x8*)&Bs[hh * 4096 + (wc + nt * 16 + cl) * 32 + qo];
#pragma unroll
            for (int mt = 0; mt < 4; mt++)
#pragma unroll
                for (int nt = 0; nt < 4; nt++)
                    acc[mt][nt] = __builtin_amdgcn_mfma_f32_16x16x32_bf16(af[mt], bfr[nt], acc[mt][nt], 0, 0, 0);
        }
        __syncthreads();
    }

    if (z == 1) {
#pragma unroll
        for (int nt = 0; nt < 4; nt++) {
            int col = bn + wc + nt * 16 + cl;
            float bvq = bq[col];
#pragma unroll
            for (int mt = 0; mt < 4; mt++) {
                long row = bm + wr + mt * 16 + quad * 4;
#pragma unroll
                for (int r = 0; r < 4; r++) {
                    float vm = (float)valid[row + r];
                    qp[(row + r) * HDIM + col] = f2bf((acc[mt][nt][r] * vm + bvq) * QSCALE);
                }
            }
        }
    } else if (bn < 1024) {
#pragma unroll
        for (int nt = 0; nt < 4; nt++) {
            int col = bn + wc + nt * 16 + cl;
            float bvk = bk[col];
#pragma unroll
            for (int mt = 0; mt < 4; mt++) {
                long row = bm + wr + mt * 16 + quad * 4;
#pragma unroll
                for (int r = 0; r < 4; r++)
                    kp[(row + r) * HDIM + col] = f2bf(acc[mt][nt][r] + bvk);
            }
        }
    } else {
        ushort_t* Lt = pool;
        long b_ = bm >> 10, s0 = bm & 1023;
#pragma unroll
        for (int p2 = 0; p2 < 2; p2++) {
            if ((w & 1) == p2) {
#pragma unroll
                for (int nt = 0; nt < 4; nt++) {
                    int cloc = nt * 16 + cl;
                    float bvv = bv[bn - 1024 + p2 * 64 + cloc];
#pragma unroll
                    for (int mt = 0; mt < 4; mt++) {
                        int row0 = wr + mt * 16 + quad * 4;
#pragma unroll
                        for (int r = 0; r < 4; r++)
                            Lt[cloc * LT_PITCH + row0 + r] = f2bf(acc[mt][nt][r] + bvv);
                    }
                }
            }
            __syncthreads();
            int c2 = tid >> 2, quarter = tid & 3;
            long gbase = ((b_ << 10) + (bn - 1024) + p2 * 64 + c2) * 1024 + s0 + quarter * 32;
            const ushort_t* src = Lt + c2 * LT_PITCH + quarter * 32;
#pragma unroll
            for (int q8 = 0; q8 < 4; q8++)
                *(bf16x8*)(vt + gbase + q8 * 8) = *(const bf16x8*)(src + q8 * 8);
            __syncthreads();
        }
    }
}

// ---------------- kernel 2: flash attention, 32x32 swapped-QK^T -------------
// T12 restructure.  R4 post-mortem (operand-mapping derivation):
//   A-frag of mfma_32x32x16: lane -> ROW l&31;  B-frag: lane -> COL l&31;
//   D: lane -> COL l&31, row f(reg,hi)=(reg&3)+8*(reg>>2)+4*hi.
// QK^T = mfma(A=K, B=Q): D[s_local=f][q=ql]  (lane owns its q's P col). OK.
// pa (cvt_pk pairs + permlane32_swap a'=[a.lo,b.lo], b'=[a.hi,b.hi]) gives
// lane (ql,hi) elem e = P[ql][blk*16 + hi*8 + e] -- which is exactly the
// B-OPERAND layout (col=q=ql).  R4 bug: passed pa as A -> output came out
// q-row/d-col transposed vs the store.  Fix: O = mfma(A=V^T frag, B=pa):
// D[d_local=f(reg,hi)][q=ql] matches the store and the per-ql l division.
__global__ __launch_bounds__(256, 2) void attn_kernel(
    const ushort_t* __restrict__ qp, const ushort_t* __restrict__ kp,
    const ushort_t* __restrict__ vt, const float* __restrict__ mask,
    float* __restrict__ out) {
    __shared__ __align__(16) ushort_t ks[2][4096];       // [buf][s(64)][d(64)]
    __shared__ __align__(16) ushort_t vs[2][4096];       // [buf][d(64)][s(64)]
    __shared__ float mlds[1024];
    const int tid = threadIdx.x;
    const int lane = tid & 63;
    const int w = tid >> 6;          // 0..3, 32 q-rows each
    const int ql = lane & 31;
    const int hi = lane >> 5;
    const int qt = blockIdx.x, h = blockIdx.y, b = blockIdx.z;

    // staging: 2 issues x 256 thr x 16B = 8KB/tile; row = j*32 + (tid>>3),
    // source chunk pre-swizzled so linear LDS dest + swizzled read match.
    const int sr2 = tid >> 3;                         // 0..31
    const int scS = ((tid & 7) ^ (sr2 & 7)) * 8;      // elems
    const int dOf = tid * 8;                          // dest elems per half

    const long kbase = (long)b * S_LEN;
    const long vbase = (long)b * 1024 + h * HEAD_D;

    // mask -> LDS, premultiplied by log2e
    {
        float4 mv4 = *(const float4*)(mask + b * S_LEN + tid * 4);
        mlds[tid * 4 + 0] = mv4.x * 1.44269504f;
        mlds[tid * 4 + 1] = mv4.y * 1.44269504f;
        mlds[tid * 4 + 2] = mv4.z * 1.44269504f;
        mlds[tid * 4 + 3] = mv4.w * 1.44269504f;
    }

    // Q as B-fragment: lane holds q = ql, d-elems kd*16 + hi*8 + j
    const long qrow0 = (long)b * KSEL + qt * 128 + w * 32;
    bf16x8 aq[4];
#pragma unroll
    for (int kd = 0; kd < 4; kd++)
        aq[kd] = *(const bf16x8*)(qp + (qrow0 + ql) * HDIM + h * HEAD_D + kd * 16 + hi * 8);

    f32x16 O[2] = {};
    float l_loc = 0.f;

    // prologue: stage tile 0
#pragma unroll
    for (int j = 0; j < 2; j++) {
        gl_lds16(kp + (kbase + j * 32 + sr2) * (long)HDIM + h * HEAD_D + scS, &ks[0][j * 2048 + dOf]);
        gl_lds16(vt + (vbase + j * 32 + sr2) * (long)S_LEN + scS, &vs[0][j * 2048 + dOf]);
    }

    for (int c = 0; c < S_LEN / 64; c++) {
        __asm__ volatile("s_waitcnt vmcnt(0)" ::: "memory");
        __syncthreads();
        if (c + 1 < S_LEN / 64) {
            int nb = (c + 1) & 1;
#pragma unroll
            for (int j = 0; j < 2; j++) {
                gl_lds16(kp + (kbase + (c + 1) * 64 + j * 32 + sr2) * (long)HDIM + h * HEAD_D + scS,
                         &ks[nb][j * 2048 + dOf]);
                gl_lds16(vt + (vbase + j * 32 + sr2) * (long)S_LEN + (c + 1) * 64 + scS,
                         &vs[nb][j * 2048 + dOf]);
            }
        }
        const ushort_t* kb_ = ks[c & 1];
        const ushort_t* vb_ = vs[c & 1];

        // QK^T (swapped): sc[mtk] = S^T rows mtk*32..+31, cols q=ql
        f32x16 sc[2] = {};
        __builtin_amdgcn_s_setprio(1);
#pragma unroll
        for (int kd = 0; kd < 4; kd++)
#pragma unroll
            for (int mtk = 0; mtk < 2; mtk++) {
                int row = mtk * 32 + ql;
                bf16x8 af = *(const bf16x8*)&kb_[row * 64 + (((kd * 2 + hi) ^ (row & 7)) * 8)];
                sc[mtk] = __builtin_amdgcn_mfma_f32_32x32x16_bf16(af, aq[kd], sc[mtk], 0, 0, 0);
            }
        __builtin_amdgcn_s_setprio(0);

        // P = 2^(s + m*log2e); k_local = mtk*32 + (reg&3) + 8*(reg>>2) + 4*hi
#pragma unroll
        for (int mtk = 0; mtk < 2; mtk++)
#pragma unroll
            for (int g = 0; g < 4; g++) {
                f32x4 m4 = *(const f32x4*)&mlds[c * 64 + mtk * 32 + g * 8 + hi * 4];
#pragma unroll
                for (int j = 0; j < 4; j++) {
                    float p_ = __builtin_amdgcn_exp2f(sc[mtk][g * 4 + j] + m4[j]);
                    sc[mtk][g * 4 + j] = p_;
                    l_loc += p_;
                }
            }

        // pack + permlane32_swap -> P fragments (B-operand layout, k-steps 16)
        bf16x8 pa[4];
#pragma unroll
        for (int mtk = 0; mtk < 2; mtk++)
#pragma unroll
            for (int sub = 0; sub < 2; sub++) {
                unsigned a0, a1, b0, b1;
                __asm__("v_cvt_pk_bf16_f32 %0, %1, %2" : "=v"(a0)
                        : "v"(sc[mtk][sub * 8 + 0]), "v"(sc[mtk][sub * 8 + 1]));
                __asm__("v_cvt_pk_bf16_f32 %0, %1, %2" : "=v"(a1)
                        : "v"(sc[mtk][sub * 8 + 2]), "v"(sc[mtk][sub * 8 + 3]));
                __asm__("v_cvt_pk_bf16_f32 %0, %1, %2" : "=v"(b0)
                        : "v"(sc[mtk][sub * 8 + 4]), "v"(sc[mtk][sub * 8 + 5]));
                __asm__("v_cvt_pk_bf16_f32 %0, %1, %2" : "=v"(b1)
                        : "v"(sc[mtk][sub * 8 + 6]), "v"(sc[mtk][sub * 8 + 7]));
                __asm__("v_permlane32_swap_b32 %0, %1" : "+v"(a0), "+v"(b0));
                __asm__("v_permlane32_swap_b32 %0, %1" : "+v"(a1), "+v"(b1));
                union { unsigned u[4]; bf16x8 v; } fr;
                fr.u[0] = a0; fr.u[1] = a1; fr.u[2] = b0; fr.u[3] = b1;
                pa[mtk * 2 + sub] = fr.v;
            }

        // PV: O[ntd] += V^T(k-step) x P(k-step)   [A=V^T frag, B=pa]
        __builtin_amdgcn_s_setprio(1);
#pragma unroll
        for (int ks_ = 0; ks_ < 4; ks_++)
#pragma unroll
            for (int ntd = 0; ntd < 2; ntd++) {
                int row = ntd * 32 + ql;
                bf16x8 bvf = *(const bf16x8*)&vb_[row * 64 + (((ks_ * 2 + hi) ^ (row & 7)) * 8)];
                O[ntd] = __builtin_amdgcn_mfma_f32_32x32x16_bf16(bvf, pa[ks_], O[ntd], 0, 0, 0);
            }
        __builtin_amdgcn_s_setprio(0);
    }

    // l[q] = hi-half + lo-half partials
    l_loc += __shfl_xor(l_loc, 32, 64);

    // store: O D-layout col=q=ql, row=d = (reg&3)+8*(reg>>2)+4*hi (+ntd*32)
#pragma unroll
    for (int ntd = 0; ntd < 2; ntd++)
#pragma unroll
        for (int g = 0; g < 4; g++) {
            float4 o4;
            o4.x = O[ntd][g * 4 + 0] / l_loc;
            o4.y = O[ntd][g * 4 + 1] / l_loc;
            o4.z = O[ntd][g * 4 + 2] / l_loc;
            o4.w = O[ntd][g * 4 + 3] / l_loc;
            *(float4*)(out + (qrow0 + ql) * HDIM + h * HEAD_D + ntd * 32 + g * 8 + hi * 4) = o4;
        }
}

// ---------------- launch ----------------------------------------------------
extern "C" void kernel_launch(void* const* d_in, const int* in_sizes, int n_in,
                              void* d_out, int out_size, void* d_ws, size_t ws_size,
                              hipStream_t stream) {
    const float* hidden = (const float*)d_in[0];
    const float* mask   = (const float*)d_in[1];
    const int*   remain = (const int*)d_in[2];
    const float* Wq = (const float*)d_in[3];
    const float* bq = (const float*)d_in[4];
    const float* Wk = (const float*)d_in[5];
    const float* bk = (const float*)d_in[6];
    const float* Wv = (const float*)d_in[7];
    const float* bv = (const float*)d_in[8];
    float* out = (float*)d_out;

    // ws (~64.8MB): idx 16K | valid 16K | hbf 16.78M | wqb 2M | wkb 2M | wvb 2M
    //             | qp 8.39M | kp 16.78M | vt 16.78M     (wkb||wvb contiguous!)
    char* ws = (char*)d_ws;
    size_t off = 0;
    int* idx   = (int*)(ws + off); off += 16384;
    int* valid = (int*)(ws + off); off += 16384;
    ushort_t* hbf = (ushort_t*)(ws + off); off += (size_t)BATCH * S_LEN * HDIM * 2;
    ushort_t* wqb = (ushort_t*)(ws + off); off += (size_t)HDIM * HDIM * 2;
    ushort_t* wkb = (ushort_t*)(ws + off); off += (size_t)HDIM * HDIM * 2;
    ushort_t* wvb = (ushort_t*)(ws + off); off += (size_t)HDIM * HDIM * 2;
    ushort_t* qp  = (ushort_t*)(ws + off); off += (size_t)BATCH * KSEL * HDIM * 2;
    ushort_t* kp  = (ushort_t*)(ws + off); off += (size_t)BATCH * S_LEN * HDIM * 2;
    ushort_t* vt  = (ushort_t*)(ws + off); off += (size_t)BATCH * S_LEN * HDIM * 2;

    prep_kernel<<<2824, 1024, 0, stream>>>(hidden, Wq, Wk, Wv, remain,
                                           hbf, wqb, wkb, wvb, idx, valid);
    gemm_fused<<<1280, 256, 0, stream>>>(hbf, wkb, wqb, bk, bv, bq,
                                         idx, valid, kp, vt, qp);
    attn_kernel<<<dim3(4, NHEADS, BATCH), 256, 0, stream>>>(qp, kp, vt, mask, out);
}

// Round 6
// 187.055 us; speedup vs baseline: 1.1289x; 1.0179x over previous
//
#include <hip/hip_runtime.h>
#include <hip/hip_bf16.h>
#include <stdint.h>

#define S_LEN 1024
#define HDIM  1024
#define NHEADS 16
#define HEAD_D 64
#define KSEL  512
#define BATCH 8

typedef unsigned short ushort_t;
typedef __attribute__((ext_vector_type(8))) __bf16 bf16x8;
typedef __attribute__((ext_vector_type(4))) float  f32x4;
typedef __attribute__((ext_vector_type(16))) float f32x16;

typedef const __attribute__((address_space(1))) void cg_void;
typedef __attribute__((address_space(3))) void lds_void;

__device__ __forceinline__ void gl_lds16(const void* g, void* l) {
    __builtin_amdgcn_global_load_lds((cg_void*)g, (lds_void*)l, 16, 0, 0);
}

// round-to-nearest-even f32 -> bf16 (finite inputs only)
__device__ __forceinline__ ushort_t f2bf(float f) {
    union { float f; unsigned int i; } x; x.f = f;
    unsigned int r = (x.i + 0x7fffu + ((x.i >> 16) & 1u)) >> 16;
    return (ushort_t)r;
}

#define BAR() __asm__ volatile("s_barrier" ::: "memory")
#define VMCNT(n) __asm__ volatile("s_waitcnt vmcnt(" #n ")" ::: "memory")
#define LGKM0() __asm__ volatile("s_waitcnt lgkmcnt(0)" ::: "memory")

// ---------------- kernel 0: prep = cvt(hidden,Wq,Wk,Wv) + compact -----------
__global__ __launch_bounds__(1024) void prep_kernel(
    const float* __restrict__ hidden, const float* __restrict__ wq,
    const float* __restrict__ wk, const float* __restrict__ wv,
    const int* __restrict__ remain,
    ushort_t* __restrict__ hbf, ushort_t* __restrict__ wqb,
    ushort_t* __restrict__ wkb, ushort_t* __restrict__ wvb,
    int* __restrict__ idx, int* __restrict__ valid) {
    __shared__ int wsum[16];
    __shared__ int woff[17];
    int blk = blockIdx.x;
    if (blk < 2816) {
        const float* s; ushort_t* d; int base;
        if (blk < 2048)      { s = hidden; d = hbf; base = blk; }
        else if (blk < 2304) { s = wq; d = wqb; base = blk - 2048; }
        else if (blk < 2560) { s = wk; d = wkb; base = blk - 2304; }
        else                 { s = wv; d = wvb; base = blk - 2560; }
        int i = base * 1024 + threadIdx.x;
        float4 v = ((const float4*)s)[i];
        ushort4 o;
        o.x = f2bf(v.x); o.y = f2bf(v.y); o.z = f2bf(v.z); o.w = f2bf(v.w);
        ((ushort4*)d)[i] = o;
    } else {
        int b = blk - 2816, t = threadIdx.x;
        int r = remain[b * S_LEN + t];
        unsigned long long m = __ballot(r != 0);
        int lane = t & 63, w = t >> 6;
        int pre = __popcll(m & ((1ull << lane) - 1ull));
        if (lane == 0) wsum[w] = __popcll(m);
        __syncthreads();
        if (t == 0) { int a = 0; for (int i = 0; i < 16; i++) { woff[i] = a; a += wsum[i]; } woff[16] = a; }
        __syncthreads();
        int tot = woff[16];
        int onesBefore = woff[w] + pre;
        int slot = r ? onesBefore : (tot + (t - onesBefore));
        if (slot < KSEL) { idx[b * KSEL + slot] = t; valid[b * KSEL + slot] = r; }
    }
}

// ---------------- kernel 1: fused K/V/Q projection GEMM (R1, verified) ------
// 128^2 tiles, BK=64, 4 blocks/CU: 63.4-64.0 us.  R2/R3: 256^2 single-block
// schedules LOSE (staging-concurrency-bound).  R6 change: per-XCD block
// order m-fastest/n-slowest so the 256KB B panel is reused by 8 consecutive
// blocks and the 2MB A slab stays L2-resident across n (2.25MB < 4MB L2).
#define QSCALE 0.1803368801111244f
#define LT_PITCH 136
__global__ __launch_bounds__(256, 4) void gemm_fused(
    const ushort_t* __restrict__ hbf, const ushort_t* __restrict__ wkv,
    const ushort_t* __restrict__ wq,
    const float* __restrict__ bk, const float* __restrict__ bv,
    const float* __restrict__ bq,
    const int* __restrict__ idx, const int* __restrict__ valid,
    ushort_t* __restrict__ kp, ushort_t* __restrict__ vt, ushort_t* __restrict__ qp) {
    __shared__ __align__(16) ushort_t pool[16384];   // 32 KB: As 8192 | Bs 8192
    ushort_t* As = pool;
    ushort_t* Bs = pool + 8192;
    const int i = blockIdx.x;
    int z, bmI, bnI;
    if (i < 256) { z = 1; bmI = i >> 3; bnI = i & 7; }
    else         { z = 0; int ii = i - 256; int x = ii & 7, j = ii >> 3;
                   bmI = x * 8 + (j & 7); bnI = j >> 3; }   // m fastest per XCD
    const long bm = (long)bmI * 128;
    const int bn = bnI * 128;

    const int tid = threadIdx.x;
    const int lane = tid & 63;
    const int w = tid >> 6;
    const int quad = lane >> 4;
    const int cl = lane & 15;
    const int srow = w * 16 + (lane >> 2);
    const int fs = ((lane >> 2) & 3) ^ ((lane >> 4) & 3);
    const int scol = ((lane & 3) ^ fs) * 8;
    const int lds_off = w * 512 + lane * 8;
    const int wr = (w >> 1) * 64, wc = (w & 1) * 64;
    const int fr = (cl & 3) ^ ((cl >> 2) & 3);
    const int qo = (quad ^ fr) * 8;

    const ushort_t* W = z ? wq : wkv;

    long ab[2];
#pragma unroll
    for (int p = 0; p < 2; p++) {
        long gr = bm + p * 64 + srow;
        if (z == 0) ab[p] = gr * HDIM;
        else {
            int b_ = (int)(gr >> 9);
            int src = idx[(b_ << 9) + ((int)gr & 511)];
            ab[p] = ((long)(b_ << 10) + src) * HDIM;
        }
    }

    f32x4 acc[4][4] = {};

    for (int k0 = 0; k0 < HDIM; k0 += 64) {
#pragma unroll
        for (int p = 0; p < 2; p++)
#pragma unroll
            for (int hh = 0; hh < 2; hh++) {
                gl_lds16(hbf + ab[p] + k0 + hh * 32 + scol, &As[hh * 4096 + p * 2048 + lds_off]);
                gl_lds16(W + ((long)(bn + p * 64 + srow)) * HDIM + k0 + hh * 32 + scol,
                         &Bs[hh * 4096 + p * 2048 + lds_off]);
            }
        __syncthreads();
#pragma unroll
        for (int hh = 0; hh < 2; hh++) {
            bf16x8 af[4], bfr[4];
#pragma unroll
            for (int mt = 0; mt < 4; mt++)
                af[mt] = *(const bf16x8*)&As[hh * 4096 + (wr + mt * 16 + cl) * 32 + qo];
#pragma unroll
            for (int nt = 0; nt < 4; nt++)
                bfr[nt] = *(const bf16x8*)&Bs[hh * 4096 + (wc + nt * 16 + cl) * 32 + qo];
#pragma unroll
            for (int mt = 0; mt < 4; mt++)
#pragma unroll
                for (int nt = 0; nt < 4; nt++)
                    acc[mt][nt] = __builtin_amdgcn_mfma_f32_16x16x32_bf16(af[mt], bfr[nt], acc[mt][nt], 0, 0, 0);
        }
        __syncthreads();
    }

    if (z == 1) {
#pragma unroll
        for (int nt = 0; nt < 4; nt++) {
            int col = bn + wc + nt * 16 + cl;
            float bvq = bq[col];
#pragma unroll
            for (int mt = 0; mt < 4; mt++) {
                long row = bm + wr + mt * 16 + quad * 4;
#pragma unroll
                for (int r = 0; r < 4; r++) {
                    float vm = (float)valid[row + r];
                    qp[(row + r) * HDIM + col] = f2bf((acc[mt][nt][r] * vm + bvq) * QSCALE);
                }
            }
        }
    } else if (bn < 1024) {
#pragma unroll
        for (int nt = 0; nt < 4; nt++) {
            int col = bn + wc + nt * 16 + cl;
            float bvk = bk[col];
#pragma unroll
            for (int mt = 0; mt < 4; mt++) {
                long row = bm + wr + mt * 16 + quad * 4;
#pragma unroll
                for (int r = 0; r < 4; r++)
                    kp[(row + r) * HDIM + col] = f2bf(acc[mt][nt][r] + bvk);
            }
        }
    } else {
        ushort_t* Lt = pool;
        long b_ = bm >> 10, s0 = bm & 1023;
#pragma unroll
        for (int p2 = 0; p2 < 2; p2++) {
            if ((w & 1) == p2) {
#pragma unroll
                for (int nt = 0; nt < 4; nt++) {
                    int cloc = nt * 16 + cl;
                    float bvv = bv[bn - 1024 + p2 * 64 + cloc];
#pragma unroll
                    for (int mt = 0; mt < 4; mt++) {
                        int row0 = wr + mt * 16 + quad * 4;
#pragma unroll
                        for (int r = 0; r < 4; r++)
                            Lt[cloc * LT_PITCH + row0 + r] = f2bf(acc[mt][nt][r] + bvv);
                    }
                }
            }
            __syncthreads();
            int c2 = tid >> 2, quarter = tid & 3;
            long gbase = ((b_ << 10) + (bn - 1024) + p2 * 64 + c2) * 1024 + s0 + quarter * 32;
            const ushort_t* src = Lt + c2 * LT_PITCH + quarter * 32;
#pragma unroll
            for (int q8 = 0; q8 < 4; q8++)
                *(bf16x8*)(vt + gbase + q8 * 8) = *(const bf16x8*)(src + q8 * 8);
            __syncthreads();
        }
    }
}

// ---------------- kernel 2: flash attention, 32x32 swapped-QK^T + ring-3 ----
// R5 post-mortem: total-minus-gemm invariant across attn rewrites -> attn is
// latency-bound on the per-iter {stage -> vmcnt(0) -> barrier} drain (stage
// latency budget = 1 iter).  R6: ring-3 K/V buffers + counted vmcnt doubles
// the budget to 2 iters.  Per iter: BAR#1 (slot (c+2)%3 free: its tile c-1
// was read in iter c-1, and BAR#1 arrival implies compute(c-1) done on all
// waves) -> stage(c+2) -> vmcnt(8) (my stage(c) drained; tiles c+1,c+2 = 8
// issues remain) -> BAR#2 (all waves' stage(c) visible) -> compute(c).
// Tail: c=14 vmcnt(4), c=15 vmcnt(0).  lgkmcnt(0) once before the loop
// publishes mlds (raw s_barrier does not flush LDS queues).
__global__ __launch_bounds__(256, 2) void attn_kernel(
    const ushort_t* __restrict__ qp, const ushort_t* __restrict__ kp,
    const ushort_t* __restrict__ vt, const float* __restrict__ mask,
    float* __restrict__ out) {
    __shared__ __align__(16) ushort_t ks[3][4096];       // [slot][s(64)][d(64)]
    __shared__ __align__(16) ushort_t vs[3][4096];       // [slot][d(64)][s(64)]
    __shared__ float mlds[1024];
    const int tid = threadIdx.x;
    const int lane = tid & 63;
    const int w = tid >> 6;          // 0..3, 32 q-rows each
    const int ql = lane & 31;
    const int hi = lane >> 5;
    const int qt = blockIdx.x, h = blockIdx.y, b = blockIdx.z;

    const int sr2 = tid >> 3;                         // 0..31
    const int scS = ((tid & 7) ^ (sr2 & 7)) * 8;      // elems, pre-swizzled src
    const int dOf = tid * 8;                          // dest elems per half

    const long kbase = (long)b * S_LEN;
    const long vbase = (long)b * 1024 + h * HEAD_D;

    // mask -> LDS, premultiplied by log2e
    {
        float4 mv4 = *(const float4*)(mask + b * S_LEN + tid * 4);
        mlds[tid * 4 + 0] = mv4.x * 1.44269504f;
        mlds[tid * 4 + 1] = mv4.y * 1.44269504f;
        mlds[tid * 4 + 2] = mv4.z * 1.44269504f;
        mlds[tid * 4 + 3] = mv4.w * 1.44269504f;
    }

    // Q as B-fragment: lane holds q = ql, d-elems kd*16 + hi*8 + j
    const long qrow0 = (long)b * KSEL + qt * 128 + w * 32;
    bf16x8 aq[4];
#pragma unroll
    for (int kd = 0; kd < 4; kd++)
        aq[kd] = *(const bf16x8*)(qp + (qrow0 + ql) * HDIM + h * HEAD_D + kd * 16 + hi * 8);

    f32x16 O[2] = {};
    float l_loc = 0.f;

    auto stage = [&](int t, int slot) {
#pragma unroll
        for (int j = 0; j < 2; j++) {
            gl_lds16(kp + (kbase + t * 64 + j * 32 + sr2) * (long)HDIM + h * HEAD_D + scS,
                     &ks[slot][j * 2048 + dOf]);
            gl_lds16(vt + (vbase + j * 32 + sr2) * (long)S_LEN + t * 64 + scS,
                     &vs[slot][j * 2048 + dOf]);
        }
    };

    // prologue: tiles 0,1 into slots 0,1
    stage(0, 0);
    stage(1, 1);
    LGKM0();                       // publish mlds before first barrier

    int slotC = 0;                 // c % 3
    int slotP = 2;                 // (c+2) % 3
    for (int c = 0; c < S_LEN / 64; c++) {
        BAR();                     // #1: all waves done reading tile c-1
        if (c + 2 < S_LEN / 64) stage(c + 2, slotP);
        if (c < 14)       { VMCNT(8); }
        else if (c == 14) { VMCNT(4); }
        else              { VMCNT(0); }
        BAR();                     // #2: stage(c) visible block-wide
        const ushort_t* kb_ = ks[slotC];
        const ushort_t* vb_ = vs[slotC];

        // QK^T (swapped): sc[mtk] = S^T rows mtk*32..+31, cols q=ql
        f32x16 sc[2] = {};
        __builtin_amdgcn_s_setprio(1);
#pragma unroll
        for (int kd = 0; kd < 4; kd++)
#pragma unroll
            for (int mtk = 0; mtk < 2; mtk++) {
                int row = mtk * 32 + ql;
                bf16x8 af = *(const bf16x8*)&kb_[row * 64 + (((kd * 2 + hi) ^ (row & 7)) * 8)];
                sc[mtk] = __builtin_amdgcn_mfma_f32_32x32x16_bf16(af, aq[kd], sc[mtk], 0, 0, 0);
            }
        __builtin_amdgcn_s_setprio(0);

        // P = 2^(s + m*log2e); k_local = mtk*32 + (reg&3) + 8*(reg>>2) + 4*hi
#pragma unroll
        for (int mtk = 0; mtk < 2; mtk++)
#pragma unroll
            for (int g = 0; g < 4; g++) {
                f32x4 m4 = *(const f32x4*)&mlds[c * 64 + mtk * 32 + g * 8 + hi * 4];
#pragma unroll
                for (int j = 0; j < 4; j++) {
                    float p_ = __builtin_amdgcn_exp2f(sc[mtk][g * 4 + j] + m4[j]);
                    sc[mtk][g * 4 + j] = p_;
                    l_loc += p_;
                }
            }

        // pack + permlane32_swap -> P fragments (B-operand layout, k-steps 16)
        bf16x8 pa[4];
#pragma unroll
        for (int mtk = 0; mtk < 2; mtk++)
#pragma unroll
            for (int sub = 0; sub < 2; sub++) {
                unsigned a0, a1, b0, b1;
                __asm__("v_cvt_pk_bf16_f32 %0, %1, %2" : "=v"(a0)
                        : "v"(sc[mtk][sub * 8 + 0]), "v"(sc[mtk][sub * 8 + 1]));
                __asm__("v_cvt_pk_bf16_f32 %0, %1, %2" : "=v"(a1)
                        : "v"(sc[mtk][sub * 8 + 2]), "v"(sc[mtk][sub * 8 + 3]));
                __asm__("v_cvt_pk_bf16_f32 %0, %1, %2" : "=v"(b0)
                        : "v"(sc[mtk][sub * 8 + 4]), "v"(sc[mtk][sub * 8 + 5]));
                __asm__("v_cvt_pk_bf16_f32 %0, %1, %2" : "=v"(b1)
                        : "v"(sc[mtk][sub * 8 + 6]), "v"(sc[mtk][sub * 8 + 7]));
                __asm__("v_permlane32_swap_b32 %0, %1" : "+v"(a0), "+v"(b0));
                __asm__("v_permlane32_swap_b32 %0, %1" : "+v"(a1), "+v"(b1));
                union { unsigned u[4]; bf16x8 v; } fr;
                fr.u[0] = a0; fr.u[1] = a1; fr.u[2] = b0; fr.u[3] = b1;
                pa[mtk * 2 + sub] = fr.v;
            }

        // PV: O[ntd] += V^T(k-step) x P(k-step)   [A=V^T frag, B=pa]
        __builtin_amdgcn_s_setprio(1);
#pragma unroll
        for (int ks_ = 0; ks_ < 4; ks_++)
#pragma unroll
            for (int ntd = 0; ntd < 2; ntd++) {
                int row = ntd * 32 + ql;
                bf16x8 bvf = *(const bf16x8*)&vb_[row * 64 + (((ks_ * 2 + hi) ^ (row & 7)) * 8)];
                O[ntd] = __builtin_amdgcn_mfma_f32_32x32x16_bf16(bvf, pa[ks_], O[ntd], 0, 0, 0);
            }
        __builtin_amdgcn_s_setprio(0);

        slotC = (slotC == 2) ? 0 : slotC + 1;
        slotP = (slotP == 2) ? 0 : slotP + 1;
    }

    // l[q] = hi-half + lo-half partials
    l_loc += __shfl_xor(l_loc, 32, 64);

    // store: O D-layout col=q=ql, row=d = (reg&3)+8*(reg>>2)+4*hi (+ntd*32)
#pragma unroll
    for (int ntd = 0; ntd < 2; ntd++)
#pragma unroll
        for (int g = 0; g < 4; g++) {
            float4 o4;
            o4.x = O[ntd][g * 4 + 0] / l_loc;
            o4.y = O[ntd][g * 4 + 1] / l_loc;
            o4.z = O[ntd][g * 4 + 2] / l_loc;
            o4.w = O[ntd][g * 4 + 3] / l_loc;
            *(float4*)(out + (qrow0 + ql) * HDIM + h * HEAD_D + ntd * 32 + g * 8 + hi * 4) = o4;
        }
}

// ---------------- launch ----------------------------------------------------
extern "C" void kernel_launch(void* const* d_in, const int* in_sizes, int n_in,
                              void* d_out, int out_size, void* d_ws, size_t ws_size,
                              hipStream_t stream) {
    const float* hidden = (const float*)d_in[0];
    const float* mask   = (const float*)d_in[1];
    const int*   remain = (const int*)d_in[2];
    const float* Wq = (const float*)d_in[3];
    const float* bq = (const float*)d_in[4];
    const float* Wk = (const float*)d_in[5];
    const float* bk = (const float*)d_in[6];
    const float* Wv = (const float*)d_in[7];
    const float* bv = (const float*)d_in[8];
    float* out = (float*)d_out;

    // ws (~64.8MB): idx 16K | valid 16K | hbf 16.78M | wqb 2M | wkb 2M | wvb 2M
    //             | qp 8.39M | kp 16.78M | vt 16.78M     (wkb||wvb contiguous!)
    char* ws = (char*)d_ws;
    size_t off = 0;
    int* idx   = (int*)(ws + off); off += 16384;
    int* valid = (int*)(ws + off); off += 16384;
    ushort_t* hbf = (ushort_t*)(ws + off); off += (size_t)BATCH * S_LEN * HDIM * 2;
    ushort_t* wqb = (ushort_t*)(ws + off); off += (size_t)HDIM * HDIM * 2;
    ushort_t* wkb = (ushort_t*)(ws + off); off += (size_t)HDIM * HDIM * 2;
    ushort_t* wvb = (ushort_t*)(ws + off); off += (size_t)HDIM * HDIM * 2;
    ushort_t* qp  = (ushort_t*)(ws + off); off += (size_t)BATCH * KSEL * HDIM * 2;
    ushort_t* kp  = (ushort_t*)(ws + off); off += (size_t)BATCH * S_LEN * HDIM * 2;
    ushort_t* vt  = (ushort_t*)(ws + off); off += (size_t)BATCH * S_LEN * HDIM * 2;

    prep_kernel<<<2824, 1024, 0, stream>>>(hidden, Wq, Wk, Wv, remain,
                                           hbf, wqb, wkb, wvb, idx, valid);
    gemm_fused<<<1280, 256, 0, stream>>>(hbf, wkb, wqb, bk, bv, bq,
                                         idx, valid, kp, vt, qp);
    attn_kernel<<<dim3(4, NHEADS, BATCH), 256, 0, stream>>>(qp, kp, vt, mask, out);
}